// Round 3
// baseline (556.527 us; speedup 1.0000x reference)
//
#include <hip/hip_runtime.h>

// MoE expert FFN: T=256, E=16, H=2048, I=1024, top_k=4 (int32 device scalar).
// Inputs fp32 (proven: bf16-reinterp gave NaN in R1). Output fp32 (proven:
// R2 wrote valid bf16, harness read fp32 -> exact stub error).
// Compute: bf16 MFMA (threshold is 2% of max|ref| -> bf16 precision OK).
//
// R2 profile: top-5 dispatches are the harness's 1 GiB ws-poison fill
// (~160us @84% HBM, in the timed window). Gemms are grid-capped at
// 1 block/CU (2 waves/SIMD) and un-pipelined -> ~1 TB/s weight stream.
// R5: 4-way in-block split-K + 16-wide i/h tiles -> 1024/2048 blocks
// (3-4 blocks/CU, 12-16 waves/CU), register prefetch of next k-iter's
// weight loads (clamped addr on last iter). Weight traffic unchanged
// (256+128 MB streamed once). MT cap 8 so counts<=128 take one ms-pass.
//
//   convert_x    : x fp32 -> bf16 xb (2 MB read, once)
//   route_kernel : softmax+topk -> per-expert token lists + per-token map
//   gemm1_kernel : h = X_e @ w1[e]^T, fused silu(gate)*up -> act (bf16 ws)
//   gemm2_kernel : y = act_e @ w2[e]^T -> y (bf16 ws)
//   gather_kernel: out[t] = sum_k wt[k]*y[e_k][slot_k]  (fp32 out, no atomics)

typedef __attribute__((ext_vector_type(8))) short bf16x8;   // MFMA A/B frag (4 VGPRs)
typedef __attribute__((ext_vector_type(4))) float floatx4;  // MFMA C/D frag

#define T_TOK 256
#define N_EXP 16
#define H_DIM 2048
#define I_DIM 1024
#define MAX_SLOTS 256
#define KQ1 (H_DIM / 4)   // 512 k per wave (gemm1 k-quarter)
#define KQ2 (I_DIM / 4)   // 256 k per wave (gemm2 k-quarter)

__device__ __forceinline__ short f2bf(float f) {           // RNE fp32->bf16
    union { float f; unsigned u; } v; v.f = f;
    unsigned r = (v.u + 0x7FFFu + ((v.u >> 16) & 1u)) >> 16;
    return (short)r;
}
__device__ __forceinline__ float bf2f(short s) {
    union { unsigned u; float f; } v; v.u = ((unsigned)(unsigned short)s) << 16;
    return v.f;
}
__device__ __forceinline__ bf16x8 pack2f4(float4 a, float4 b) {  // 8 fp32 -> bf16x8
    bf16x8 r;
    r[0] = f2bf(a.x); r[1] = f2bf(a.y); r[2] = f2bf(a.z); r[3] = f2bf(a.w);
    r[4] = f2bf(b.x); r[5] = f2bf(b.y); r[6] = f2bf(b.z); r[7] = f2bf(b.w);
    return r;
}
__device__ __forceinline__ bf16x8 pack8(const float* __restrict__ p) {
    return pack2f4(*(const float4*)p, *(const float4*)(p + 4));
}

// ---------------- x fp32 -> bf16 ----------------
__global__ __launch_bounds__(256) void convert_x_kernel(
    const float* __restrict__ xf, short* __restrict__ xb)
{
    const int i = (blockIdx.x * 256 + threadIdx.x) * 8;   // 65536 threads * 8 = 524288
    *(bf16x8*)(xb + i) = pack8(xf + i);
}

// ---------------- routing ----------------
__global__ __launch_bounds__(256) void route_kernel(
    const float* __restrict__ logits,   // [256][16] fp32
    const int* __restrict__ topk_ptr,
    int* __restrict__ counts, int* __restrict__ tokens,
    int* __restrict__ tok_e, int* __restrict__ tok_slot, float* __restrict__ tok_wt)
{
    __shared__ int lds_counts[N_EXP];
    const int t = threadIdx.x;
    if (t < N_EXP) lds_counts[t] = 0;
    __syncthreads();

    int K = topk_ptr[0];
    if (K > 8) K = 8;
    if (K < 1) K = 1;

    float l[N_EXP];
    #pragma unroll
    for (int j = 0; j < N_EXP; ++j) l[j] = logits[t * N_EXP + j];

    float M = l[0];
    #pragma unroll
    for (int j = 1; j < N_EXP; ++j) M = fmaxf(M, l[j]);

    // top-K by logit; strict > keeps lowest index on ties (matches lax.top_k)
    int idx[8]; float lv[8]; unsigned used = 0u;
    for (int k = 0; k < K; ++k) {
        int bi = 0; float bv = -1e30f;
        #pragma unroll
        for (int j = 0; j < N_EXP; ++j)
            if (!((used >> j) & 1u) && l[j] > bv) { bv = l[j]; bi = j; }
        used |= 1u << bi;
        idx[k] = bi; lv[k] = bv;
    }
    // softmax restricted to top-K == renormalized top-K softmax probs
    float w[8], s = 0.f;
    for (int k = 0; k < K; ++k) { w[k] = __expf(lv[k] - M); s += w[k]; }
    const float inv = 1.0f / s;

    for (int k = 0; k < K; ++k) {
        const int e = idx[k];
        const int slot = atomicAdd(&lds_counts[e], 1);
        tokens[e * MAX_SLOTS + slot] = t;
        tok_e[t * 8 + k] = e; tok_slot[t * 8 + k] = slot; tok_wt[t * 8 + k] = w[k] * inv;
    }
    __syncthreads();
    if (t < N_EXP) counts[t] = lds_counts[t];
}

// ---------------- GEMM1: h = X_e @ w1[e]^T, act = silu(gate)*up ----------------
// grid (16 experts, 64 i-blocks of 16). 256 threads = 4 waves = 4 k-quarters
// (wave kq covers k in [kq*512, kq*512+512)). Waves 1..3 write partial acc to
// LDS; wave 0 sums all four + silu + store. Both weight AND A-row offsets
// carry kq*KQ1 (R4 lesson). Next k-iter's 4 weight loads are register-
// prefetched (clamped addr on last iter -> no OOB, harmless L1-hit reload).
template<int MT>
__device__ __forceinline__ void g1_ms(
    int ms, int count, const int* __restrict__ toks, const short* __restrict__ xb,
    const float* __restrict__ wg, const float* __restrict__ wu,
    int quad, int nl, int lane, int kq, int i_base, int e,
    short* __restrict__ act, floatx4* red)
{
    int xoff[MT];
    #pragma unroll
    for (int mt = 0; mt < MT; ++mt) {
        int s = ms + mt * 16 + nl;
        if (s >= count) s = count - 1;     // clamp: padded rows dropped at store
        xoff[mt] = toks[s] * H_DIM + kq * KQ1;
    }
    floatx4 ag[MT], au[MT];
    #pragma unroll
    for (int mt = 0; mt < MT; ++mt) { ag[mt] = (floatx4)0.0f; au[mt] = (floatx4)0.0f; }

    const int koff = quad * 8;
    float4 g0 = *(const float4*)(wg + koff), g1 = *(const float4*)(wg + koff + 4);
    float4 u0 = *(const float4*)(wu + koff), u1 = *(const float4*)(wu + koff + 4);

    for (int k = 0; k < KQ1; k += 32) {
        const int nk = (k + 32 < KQ1) ? (k + 32) : k;   // clamped prefetch
        float4 ng0 = *(const float4*)(wg + nk + koff);
        float4 ng1 = *(const float4*)(wg + nk + koff + 4);
        float4 nu0 = *(const float4*)(wu + nk + koff);
        float4 nu1 = *(const float4*)(wu + nk + koff + 4);
        bf16x8 av[MT];
        #pragma unroll
        for (int mt = 0; mt < MT; ++mt) av[mt] = *(const bf16x8*)(xb + xoff[mt] + k + koff);
        bf16x8 bg = pack2f4(g0, g1);
        bf16x8 bu = pack2f4(u0, u1);
        #pragma unroll
        for (int mt = 0; mt < MT; ++mt) {
            ag[mt] = __builtin_amdgcn_mfma_f32_16x16x32_bf16(av[mt], bg, ag[mt], 0, 0, 0);
            au[mt] = __builtin_amdgcn_mfma_f32_16x16x32_bf16(av[mt], bu, au[mt], 0, 0, 0);
        }
        g0 = ng0; g1 = ng1; u0 = nu0; u1 = nu1;
    }
    // cross-quarter reduction via LDS: fixed layout [kq-1][8][g/u][64] floatx4
    if (kq) {
        #pragma unroll
        for (int mt = 0; mt < MT; ++mt) {
            red[(((kq - 1) * 8 + mt) * 2 + 0) * 64 + lane] = ag[mt];
            red[(((kq - 1) * 8 + mt) * 2 + 1) * 64 + lane] = au[mt];
        }
    }
    __syncthreads();
    if (kq == 0) {
        #pragma unroll
        for (int mt = 0; mt < MT; ++mt) {
            floatx4 g = ag[mt], u = au[mt];
            #pragma unroll
            for (int q = 0; q < 3; ++q) {
                g += red[((q * 8 + mt) * 2 + 0) * 64 + lane];
                u += red[((q * 8 + mt) * 2 + 1) * 64 + lane];
            }
            #pragma unroll
            for (int r = 0; r < 4; ++r) {
                const int slot = ms + mt * 16 + quad * 4 + r;   // D: row=quad*4+r, col=nl
                if (slot < count) {
                    const float gv = g[r], uv = u[r];
                    const float a = gv / (1.0f + __expf(-gv)) * uv;   // silu(g)*u
                    act[(size_t)(e * MAX_SLOTS + slot) * I_DIM + i_base + nl] = f2bf(a);
                }
            }
        }
    }
    __syncthreads();   // protect LDS reuse on next ms iteration
}

__global__ __launch_bounds__(256, 3) void gemm1_kernel(
    const short* __restrict__ xb,     // [256][2048] bf16
    const float* __restrict__ w1,     // [16][2048][2048] fp32
    const int* __restrict__ counts, const int* __restrict__ tokens,
    short* __restrict__ act)          // [16][256][1024] bf16
{
    __shared__ floatx4 red[3 * 8 * 2 * 64];    // 48 KB -> 3 blocks/CU
    const int e = blockIdx.x;
    const int count = counts[e];
    if (count == 0) return;
    const int tid = (int)threadIdx.x;
    const int kq = tid >> 6, lane = tid & 63;
    const int nl = lane & 15, quad = lane >> 4;
    const int i_base = blockIdx.y * 16;

    const float* wg = w1 + ((size_t)e * H_DIM + (i_base + nl)) * H_DIM + kq * KQ1;
    const float* wu = w1 + ((size_t)e * H_DIM + (I_DIM + i_base + nl)) * H_DIM + kq * KQ1;
    const int* toks = tokens + e * MAX_SLOTS;

    for (int ms = 0; ms < count; ms += 128) {
        const int rem = count - ms;
        const int nmt = rem >= 128 ? 8 : ((rem + 15) >> 4);   // block-uniform
        switch (nmt) {
            case 1: g1_ms<1>(ms, count, toks, xb, wg, wu, quad, nl, lane, kq, i_base, e, act, red); break;
            case 2: g1_ms<2>(ms, count, toks, xb, wg, wu, quad, nl, lane, kq, i_base, e, act, red); break;
            case 3: g1_ms<3>(ms, count, toks, xb, wg, wu, quad, nl, lane, kq, i_base, e, act, red); break;
            case 4: g1_ms<4>(ms, count, toks, xb, wg, wu, quad, nl, lane, kq, i_base, e, act, red); break;
            case 5: g1_ms<5>(ms, count, toks, xb, wg, wu, quad, nl, lane, kq, i_base, e, act, red); break;
            case 6: g1_ms<6>(ms, count, toks, xb, wg, wu, quad, nl, lane, kq, i_base, e, act, red); break;
            case 7: g1_ms<7>(ms, count, toks, xb, wg, wu, quad, nl, lane, kq, i_base, e, act, red); break;
            default: g1_ms<8>(ms, count, toks, xb, wg, wu, quad, nl, lane, kq, i_base, e, act, red); break;
        }
    }
}

// ---------------- GEMM2: y = act_e @ w2[e]^T ----------------
// grid (16 experts, 128 h-blocks of 16). 256 threads = 4 waves = 4 k-quarters.
template<int MT>
__device__ __forceinline__ void g2_ms(
    int ms, int count, const short* __restrict__ acte,
    const float* __restrict__ wr,
    int quad, int nl, int lane, int kq, int h_base, int e,
    short* __restrict__ y, floatx4* red)
{
    int aoff[MT];
    #pragma unroll
    for (int mt = 0; mt < MT; ++mt) {
        int s = ms + mt * 16 + nl;
        if (s >= count) s = count - 1;
        aoff[mt] = s * I_DIM + kq * KQ2;
    }
    floatx4 acc[MT];
    #pragma unroll
    for (int mt = 0; mt < MT; ++mt) acc[mt] = (floatx4)0.0f;

    const int koff = quad * 8;
    float4 b0 = *(const float4*)(wr + koff), b1 = *(const float4*)(wr + koff + 4);

    for (int k = 0; k < KQ2; k += 32) {
        const int nk = (k + 32 < KQ2) ? (k + 32) : k;
        float4 nb0 = *(const float4*)(wr + nk + koff);
        float4 nb1 = *(const float4*)(wr + nk + koff + 4);
        bf16x8 av[MT];
        #pragma unroll
        for (int mt = 0; mt < MT; ++mt) av[mt] = *(const bf16x8*)(acte + aoff[mt] + k + koff);
        bf16x8 b = pack2f4(b0, b1);
        #pragma unroll
        for (int mt = 0; mt < MT; ++mt)
            acc[mt] = __builtin_amdgcn_mfma_f32_16x16x32_bf16(av[mt], b, acc[mt], 0, 0, 0);
        b0 = nb0; b1 = nb1;
    }
    if (kq) {
        #pragma unroll
        for (int mt = 0; mt < MT; ++mt) red[((kq - 1) * 8 + mt) * 64 + lane] = acc[mt];
    }
    __syncthreads();
    if (kq == 0) {
        #pragma unroll
        for (int mt = 0; mt < MT; ++mt) {
            floatx4 a = acc[mt];
            #pragma unroll
            for (int q = 0; q < 3; ++q) a += red[(q * 8 + mt) * 64 + lane];
            #pragma unroll
            for (int r = 0; r < 4; ++r) {
                const int slot = ms + mt * 16 + quad * 4 + r;
                if (slot < count)
                    y[(size_t)(e * MAX_SLOTS + slot) * H_DIM + h_base + nl] = f2bf(a[r]);
            }
        }
    }
    __syncthreads();
}

__global__ __launch_bounds__(256, 4) void gemm2_kernel(
    const short* __restrict__ act,    // [16][256][1024] bf16
    const float* __restrict__ w2,     // [16][2048][1024] fp32
    const int* __restrict__ counts,
    short* __restrict__ y)            // [16][256][2048] bf16
{
    __shared__ floatx4 red[3 * 8 * 64];    // 24 KB -> 4+ blocks/CU
    const int e = blockIdx.x;
    const int count = counts[e];
    if (count == 0) return;
    const int tid = (int)threadIdx.x;
    const int kq = tid >> 6, lane = tid & 63;
    const int nl = lane & 15, quad = lane >> 4;
    const int h_base = blockIdx.y * 16;

    const float* wr = w2 + ((size_t)e * H_DIM + h_base + nl) * I_DIM + kq * KQ2;
    const short* acte = act + (size_t)e * MAX_SLOTS * I_DIM;

    for (int ms = 0; ms < count; ms += 128) {
        const int rem = count - ms;
        const int nmt = rem >= 128 ? 8 : ((rem + 15) >> 4);
        switch (nmt) {
            case 1: g2_ms<1>(ms, count, acte, wr, quad, nl, lane, kq, h_base, e, y, red); break;
            case 2: g2_ms<2>(ms, count, acte, wr, quad, nl, lane, kq, h_base, e, y, red); break;
            case 3: g2_ms<3>(ms, count, acte, wr, quad, nl, lane, kq, h_base, e, y, red); break;
            case 4: g2_ms<4>(ms, count, acte, wr, quad, nl, lane, kq, h_base, e, y, red); break;
            case 5: g2_ms<5>(ms, count, acte, wr, quad, nl, lane, kq, h_base, e, y, red); break;
            case 6: g2_ms<6>(ms, count, acte, wr, quad, nl, lane, kq, h_base, e, y, red); break;
            case 7: g2_ms<7>(ms, count, acte, wr, quad, nl, lane, kq, h_base, e, y, red); break;
            default: g2_ms<8>(ms, count, acte, wr, quad, nl, lane, kq, h_base, e, y, red); break;
        }
    }
}

// ---------------- gather: out[t][h] = sum_k wt * y[e_k][slot_k][h] (fp32) ----------------
__global__ __launch_bounds__(256) void gather_kernel(
    const short* __restrict__ y, const int* __restrict__ topk_ptr,
    const int* __restrict__ tok_e, const int* __restrict__ tok_slot,
    const float* __restrict__ tok_wt, float* __restrict__ out)
{
    const int t = blockIdx.x;
    int K = topk_ptr[0];
    if (K > 8) K = 8;
    if (K < 1) K = 1;
    int e[8], sl[8]; float w[8];
    for (int k = 0; k < K; ++k) {
        e[k] = tok_e[t * 8 + k]; sl[k] = tok_slot[t * 8 + k]; w[k] = tok_wt[t * 8 + k];
    }
    for (int h = threadIdx.x; h < H_DIM; h += 256) {
        float s = 0.f;
        for (int k = 0; k < K; ++k)
            s += w[k] * bf2f(y[(size_t)(e[k] * MAX_SLOTS + sl[k]) * H_DIM + h]);
        out[(size_t)t * H_DIM + h] = s;
    }
}

// ---------------- launch ----------------
extern "C" void kernel_launch(void* const* d_in, const int* in_sizes, int n_in,
                              void* d_out, int out_size, void* d_ws, size_t ws_size,
                              hipStream_t stream)
{
    const float* x  = (const float*)d_in[0];
    const float* rl = (const float*)d_in[1];
    const float* w1 = (const float*)d_in[2];
    const float* w2 = (const float*)d_in[3];
    const int* topk = (const int*)d_in[4];

    char* ws = (char*)d_ws;
    int*   counts   = (int*)  (ws + 0);          //   64 B
    int*   tokens   = (int*)  (ws + 256);        //  16 KB [16][256]
    int*   tok_e    = (int*)  (ws + 16640);      //   8 KB [256][8]
    int*   tok_slot = (int*)  (ws + 24832);      //   8 KB
    float* tok_wt   = (float*)(ws + 33024);      //   8 KB
    short* xb       = (short*)(ws + 65536);      //   1 MB [256][2048] bf16
    short* act      = (short*)(ws + 1114112);    //   8 MB [16][256][1024] bf16
    short* yb       = (short*)(ws + 9502720);    //  16 MB [16][256][2048] bf16

    convert_x_kernel<<<256, 256, 0, stream>>>(x, xb);
    route_kernel<<<1, 256, 0, stream>>>(rl, topk, counts, tokens, tok_e, tok_slot, tok_wt);
    gemm1_kernel<<<dim3(N_EXP, 64), 256, 0, stream>>>(xb, w1, counts, tokens, act);
    gemm2_kernel<<<dim3(N_EXP, 128), 256, 0, stream>>>(act, w2, counts, yb);
    gather_kernel<<<T_TOK, 256, 0, stream>>>(yb, topk, tok_e, tok_slot, tok_wt, (float*)d_out);
}

// Round 4
// 504.133 us; speedup vs baseline: 1.1039x; 1.1039x over previous
//
#include <hip/hip_runtime.h>

// MoE expert FFN: T=256, E=16, H=2048, I=1024, top_k=4 (int32 device scalar).
// Inputs fp32 (proven: bf16-reinterp gave NaN). Output fp32 (proven). Compute
// bf16 MFMA (threshold 2% of max|ref|).
//
// R6: gemms rebuilt as LDS-staged burst streams (T14 issue-early/write-late).
// Prior versions kept ~1KB/wave in flight (R0: 637 GB/s) — latency-bound.
// Now: per K-step, 512 threads issue 40KB of global loads in one burst
// (weights fp32 -> regs -> convert -> LDS bf16; activations bf16 -> LDS),
// MFMA-compute the current double-buffered tile, then write+barrier.
// Weights stream exactly once (MT=8, ms-step 128). BN=128, BK=64,
// grid (16,16), 8 waves/block, LDS 72KB (rows padded to 72 shorts = 144B
// stride -> <=4-way bank aliasing instead of 16-way).
//
//   convert_x    : x fp32 -> bf16 xb (2 MB, once)
//   route_kernel : softmax+topk -> per-expert token lists + per-token map
//   gemm1_kernel : h = X_e @ w1[e]^T, fused silu(gate)*up -> act (bf16 ws)
//   gemm2_kernel : y = act_e @ w2[e]^T -> y (bf16 ws)
//   gather_kernel: out[t] = sum_k wt[k]*y[e_k][slot_k]  (fp32 out)

typedef __attribute__((ext_vector_type(8))) short bf16x8;   // MFMA A/B frag
typedef __attribute__((ext_vector_type(4))) float floatx4;  // MFMA C/D frag

#define T_TOK 256
#define N_EXP 16
#define H_DIM 2048
#define I_DIM 1024
#define MAX_SLOTS 256
#define BK 64
#define LDW 72                    // padded LDS row stride (shorts); 144B = 9*16B
#define TILE (128 * LDW)          // shorts per tile buffer
#define NT1 (H_DIM / BK)          // 32 K-steps (gemm1)
#define NT2 (I_DIM / BK)          // 16 K-steps (gemm2)

__device__ __forceinline__ short f2bf(float f) {           // RNE fp32->bf16
    union { float f; unsigned u; } v; v.f = f;
    unsigned r = (v.u + 0x7FFFu + ((v.u >> 16) & 1u)) >> 16;
    return (short)r;
}
__device__ __forceinline__ float bf2f(short s) {
    union { unsigned u; float f; } v; v.u = ((unsigned)(unsigned short)s) << 16;
    return v.f;
}
__device__ __forceinline__ bf16x8 pack2f4(float4 a, float4 b) {  // 8 fp32 -> bf16x8
    bf16x8 r;
    r[0] = f2bf(a.x); r[1] = f2bf(a.y); r[2] = f2bf(a.z); r[3] = f2bf(a.w);
    r[4] = f2bf(b.x); r[5] = f2bf(b.y); r[6] = f2bf(b.z); r[7] = f2bf(b.w);
    return r;
}
__device__ __forceinline__ bf16x8 pack8(const float* __restrict__ p) {
    return pack2f4(*(const float4*)p, *(const float4*)(p + 4));
}

// ---------------- x fp32 -> bf16 ----------------
__global__ __launch_bounds__(256) void convert_x_kernel(
    const float* __restrict__ xf, short* __restrict__ xb)
{
    const int i = (blockIdx.x * 256 + threadIdx.x) * 8;
    *(bf16x8*)(xb + i) = pack8(xf + i);
}

// ---------------- routing ----------------
__global__ __launch_bounds__(256) void route_kernel(
    const float* __restrict__ logits,   // [256][16] fp32
    const int* __restrict__ topk_ptr,
    int* __restrict__ counts, int* __restrict__ tokens,
    int* __restrict__ tok_e, int* __restrict__ tok_slot, float* __restrict__ tok_wt)
{
    __shared__ int lds_counts[N_EXP];
    const int t = threadIdx.x;
    if (t < N_EXP) lds_counts[t] = 0;
    __syncthreads();

    int K = topk_ptr[0];
    if (K > 8) K = 8;
    if (K < 1) K = 1;

    float l[N_EXP];
    #pragma unroll
    for (int j = 0; j < N_EXP; ++j) l[j] = logits[t * N_EXP + j];

    float M = l[0];
    #pragma unroll
    for (int j = 1; j < N_EXP; ++j) M = fmaxf(M, l[j]);

    // top-K by logit; strict > keeps lowest index on ties (matches lax.top_k)
    int idx[8]; float lv[8]; unsigned used = 0u;
    for (int k = 0; k < K; ++k) {
        int bi = 0; float bv = -1e30f;
        #pragma unroll
        for (int j = 0; j < N_EXP; ++j)
            if (!((used >> j) & 1u) && l[j] > bv) { bv = l[j]; bi = j; }
        used |= 1u << bi;
        idx[k] = bi; lv[k] = bv;
    }
    float w[8], s = 0.f;
    for (int k = 0; k < K; ++k) { w[k] = __expf(lv[k] - M); s += w[k]; }
    const float inv = 1.0f / s;

    for (int k = 0; k < K; ++k) {
        const int e = idx[k];
        const int slot = atomicAdd(&lds_counts[e], 1);
        tokens[e * MAX_SLOTS + slot] = t;
        tok_e[t * 8 + k] = e; tok_slot[t * 8 + k] = slot; tok_wt[t * 8 + k] = w[k] * inv;
    }
    __syncthreads();
    if (t < N_EXP) counts[t] = lds_counts[t];
}

// ---------------- GEMM1: act = silu(X_e @ Wg^T) * (X_e @ Wu^T) ----------------
// grid (16 experts, 16 i-blocks of 64). 512 threads = 8 waves.
// B-tile = 128 w1 rows: rows 0..63 = gate rows i_base+j, 64..127 = up rows
// 1024+i_base+j. Wave: gu=wave>>2 (gate/up), iw=wave&3 -> rows gu*64+iw*16+nl.
// A-tile = 128 token rows (slots ms..ms+127, clamped). Double-buffered LDS,
// burst-staged: loads for kt+1 issue BEFORE compute(kt), LDS writes after.
__global__ __launch_bounds__(512, 2) void gemm1_kernel(
    const short* __restrict__ xb,     // [256][2048] bf16
    const float* __restrict__ w1,     // [16][2048][2048] fp32
    const int* __restrict__ counts, const int* __restrict__ tokens,
    short* __restrict__ act)          // [16][256][1024] bf16
{
    __shared__ short lds[4 * TILE];   // A0 A1 B0 B1 = 72 KB
    const int e = blockIdx.x;
    const int count = counts[e];
    if (count == 0) return;
    const int tid = (int)threadIdx.x;
    const int wave = tid >> 6, lane = tid & 63;
    const int gu = wave >> 2, iw = wave & 3;
    const int nl = lane & 15, quad = lane >> 4;
    const int i_base = blockIdx.y * 64;
    const int* toks = tokens + e * MAX_SLOTS;

    // staging coords: thread t covers tile row sr = t/4, 16 elems at col sk
    const int sr = tid >> 2;
    const int sk = (tid & 3) << 4;
    const int w1row = i_base + (sr & 63) + ((sr >> 6) << 10);   // gate | up
    const float* wsrc = w1 + ((size_t)e * H_DIM + w1row) * H_DIM + sk;
    const int st = sr * LDW + sk;     // LDS offset (shorts)

    for (int ms = 0; ms < count; ms += 128) {
        int slotS = ms + sr; if (slotS >= count) slotS = count - 1;  // clamp
        const short* asrc = xb + (size_t)toks[slotS] * H_DIM + sk;

        floatx4 acc[8];
        #pragma unroll
        for (int mt = 0; mt < 8; ++mt) acc[mt] = (floatx4)0.0f;

        // prologue: stage kt=0 into buffers 0
        {
            float4 b0 = *(const float4*)(wsrc + 0), b1 = *(const float4*)(wsrc + 4);
            float4 b2 = *(const float4*)(wsrc + 8), b3 = *(const float4*)(wsrc + 12);
            bf16x8 a0 = *(const bf16x8*)(asrc + 0), a1 = *(const bf16x8*)(asrc + 8);
            *(bf16x8*)(lds + 0 * TILE + st) = a0;
            *(bf16x8*)(lds + 0 * TILE + st + 8) = a1;
            *(bf16x8*)(lds + 2 * TILE + st) = pack2f4(b0, b1);
            *(bf16x8*)(lds + 2 * TILE + st + 8) = pack2f4(b2, b3);
        }
        __syncthreads();

        for (int kt = 0; kt < NT1; ++kt) {
            const int cur = kt & 1, nxt = cur ^ 1;
            const bool pf = (kt + 1 < NT1);
            float4 b0, b1, b2, b3; bf16x8 a0, a1;
            if (pf) {                                  // issue-early (T14)
                const float* ws = wsrc + (kt + 1) * BK;
                const short* as = asrc + (kt + 1) * BK;
                b0 = *(const float4*)(ws + 0);  b1 = *(const float4*)(ws + 4);
                b2 = *(const float4*)(ws + 8);  b3 = *(const float4*)(ws + 12);
                a0 = *(const bf16x8*)(as + 0);  a1 = *(const bf16x8*)(as + 8);
            }
            const short* A = lds + cur * TILE;
            const short* B = lds + (2 + cur) * TILE;
            #pragma unroll
            for (int c = 0; c < 2; ++c) {
                bf16x8 bf = *(const bf16x8*)(B + (gu * 64 + iw * 16 + nl) * LDW + c * 32 + quad * 8);
                #pragma unroll
                for (int mt = 0; mt < 8; ++mt) {
                    bf16x8 af = *(const bf16x8*)(A + (mt * 16 + nl) * LDW + c * 32 + quad * 8);
                    acc[mt] = __builtin_amdgcn_mfma_f32_16x16x32_bf16(af, bf, acc[mt], 0, 0, 0);
                }
            }
            if (pf) {                                  // write-late
                *(bf16x8*)(lds + nxt * TILE + st) = a0;
                *(bf16x8*)(lds + nxt * TILE + st + 8) = a1;
                *(bf16x8*)(lds + (2 + nxt) * TILE + st) = pack2f4(b0, b1);
                *(bf16x8*)(lds + (2 + nxt) * TILE + st + 8) = pack2f4(b2, b3);
            }
            __syncthreads();
        }

        // epilogue: up waves publish acc via LDS; gate waves silu+store.
        floatx4* epi = (floatx4*)lds;   // 32 KB alias (safe after barrier)
        if (gu == 1) {
            #pragma unroll
            for (int mt = 0; mt < 8; ++mt) epi[(iw * 8 + mt) * 64 + lane] = acc[mt];
        }
        __syncthreads();
        if (gu == 0) {
            #pragma unroll
            for (int mt = 0; mt < 8; ++mt) {
                floatx4 u = epi[(iw * 8 + mt) * 64 + lane];
                #pragma unroll
                for (int r = 0; r < 4; ++r) {
                    const int slot = ms + mt * 16 + quad * 4 + r;   // D: row=quad*4+r, col=nl
                    if (slot < count) {
                        const float g = acc[mt][r], uv = u[r];
                        const float a = g / (1.0f + __expf(-g)) * uv;   // silu(g)*u
                        act[(size_t)(e * MAX_SLOTS + slot) * I_DIM + i_base + iw * 16 + nl] = f2bf(a);
                    }
                }
            }
        }
        __syncthreads();   // lds reused by next ms pass
    }
}

// ---------------- GEMM2: y = act_e @ w2[e]^T ----------------
// grid (16 experts, 16 h-blocks of 128). 512 threads = 8 waves; wave owns
// h-rows wave*16+nl. Same burst-staged double-buffer structure; no reduce.
__global__ __launch_bounds__(512, 2) void gemm2_kernel(
    const short* __restrict__ act,    // [16][256][1024] bf16
    const float* __restrict__ w2,     // [16][2048][1024] fp32
    const int* __restrict__ counts,
    short* __restrict__ y)            // [16][256][2048] bf16
{
    __shared__ short lds[4 * TILE];
    const int e = blockIdx.x;
    const int count = counts[e];
    if (count == 0) return;
    const int tid = (int)threadIdx.x;
    const int wave = tid >> 6, lane = tid & 63;
    const int nl = lane & 15, quad = lane >> 4;
    const int h_base = blockIdx.y * 128;

    const int sr = tid >> 2;
    const int sk = (tid & 3) << 4;
    const float* wsrc = w2 + ((size_t)e * H_DIM + h_base + sr) * I_DIM + sk;
    const short* acte = act + (size_t)e * MAX_SLOTS * I_DIM;
    const int st = sr * LDW + sk;

    for (int ms = 0; ms < count; ms += 128) {
        int slotS = ms + sr; if (slotS >= count) slotS = count - 1;
        const short* asrc = acte + (size_t)slotS * I_DIM + sk;

        floatx4 acc[8];
        #pragma unroll
        for (int mt = 0; mt < 8; ++mt) acc[mt] = (floatx4)0.0f;

        {
            float4 b0 = *(const float4*)(wsrc + 0), b1 = *(const float4*)(wsrc + 4);
            float4 b2 = *(const float4*)(wsrc + 8), b3 = *(const float4*)(wsrc + 12);
            bf16x8 a0 = *(const bf16x8*)(asrc + 0), a1 = *(const bf16x8*)(asrc + 8);
            *(bf16x8*)(lds + 0 * TILE + st) = a0;
            *(bf16x8*)(lds + 0 * TILE + st + 8) = a1;
            *(bf16x8*)(lds + 2 * TILE + st) = pack2f4(b0, b1);
            *(bf16x8*)(lds + 2 * TILE + st + 8) = pack2f4(b2, b3);
        }
        __syncthreads();

        for (int kt = 0; kt < NT2; ++kt) {
            const int cur = kt & 1, nxt = cur ^ 1;
            const bool pf = (kt + 1 < NT2);
            float4 b0, b1, b2, b3; bf16x8 a0, a1;
            if (pf) {
                const float* ws = wsrc + (kt + 1) * BK;
                const short* as = asrc + (kt + 1) * BK;
                b0 = *(const float4*)(ws + 0);  b1 = *(const float4*)(ws + 4);
                b2 = *(const float4*)(ws + 8);  b3 = *(const float4*)(ws + 12);
                a0 = *(const bf16x8*)(as + 0);  a1 = *(const bf16x8*)(as + 8);
            }
            const short* A = lds + cur * TILE;
            const short* B = lds + (2 + cur) * TILE;
            #pragma unroll
            for (int c = 0; c < 2; ++c) {
                bf16x8 bf = *(const bf16x8*)(B + (wave * 16 + nl) * LDW + c * 32 + quad * 8);
                #pragma unroll
                for (int mt = 0; mt < 8; ++mt) {
                    bf16x8 af = *(const bf16x8*)(A + (mt * 16 + nl) * LDW + c * 32 + quad * 8);
                    acc[mt] = __builtin_amdgcn_mfma_f32_16x16x32_bf16(af, bf, acc[mt], 0, 0, 0);
                }
            }
            if (pf) {
                *(bf16x8*)(lds + nxt * TILE + st) = a0;
                *(bf16x8*)(lds + nxt * TILE + st + 8) = a1;
                *(bf16x8*)(lds + (2 + nxt) * TILE + st) = pack2f4(b0, b1);
                *(bf16x8*)(lds + (2 + nxt) * TILE + st + 8) = pack2f4(b2, b3);
            }
            __syncthreads();
        }

        #pragma unroll
        for (int mt = 0; mt < 8; ++mt) {
            #pragma unroll
            for (int r = 0; r < 4; ++r) {
                const int slot = ms + mt * 16 + quad * 4 + r;
                if (slot < count)
                    y[(size_t)(e * MAX_SLOTS + slot) * H_DIM + h_base + wave * 16 + nl] = f2bf(acc[mt][r]);
            }
        }
        __syncthreads();   // lds reused by next ms pass
    }
}

// ---------------- gather: out[t][h] = sum_k wt * y[e_k][slot_k][h] (fp32) ----------------
__global__ __launch_bounds__(256) void gather_kernel(
    const short* __restrict__ y, const int* __restrict__ topk_ptr,
    const int* __restrict__ tok_e, const int* __restrict__ tok_slot,
    const float* __restrict__ tok_wt, float* __restrict__ out)
{
    const int t = blockIdx.x;
    int K = topk_ptr[0];
    if (K > 8) K = 8;
    if (K < 1) K = 1;
    int e[8], sl[8]; float w[8];
    for (int k = 0; k < K; ++k) {
        e[k] = tok_e[t * 8 + k]; sl[k] = tok_slot[t * 8 + k]; w[k] = tok_wt[t * 8 + k];
    }
    for (int h = threadIdx.x; h < H_DIM; h += 256) {
        float s = 0.f;
        for (int k = 0; k < K; ++k)
            s += w[k] * bf2f(y[(size_t)(e[k] * MAX_SLOTS + sl[k]) * H_DIM + h]);
        out[(size_t)t * H_DIM + h] = s;
    }
}

// ---------------- launch ----------------
extern "C" void kernel_launch(void* const* d_in, const int* in_sizes, int n_in,
                              void* d_out, int out_size, void* d_ws, size_t ws_size,
                              hipStream_t stream)
{
    const float* x  = (const float*)d_in[0];
    const float* rl = (const float*)d_in[1];
    const float* w1 = (const float*)d_in[2];
    const float* w2 = (const float*)d_in[3];
    const int* topk = (const int*)d_in[4];

    char* ws = (char*)d_ws;
    int*   counts   = (int*)  (ws + 0);          //   64 B
    int*   tokens   = (int*)  (ws + 256);        //  16 KB [16][256]
    int*   tok_e    = (int*)  (ws + 16640);      //   8 KB [256][8]
    int*   tok_slot = (int*)  (ws + 24832);      //   8 KB
    float* tok_wt   = (float*)(ws + 33024);      //   8 KB
    short* xb       = (short*)(ws + 65536);      //   1 MB [256][2048] bf16
    short* act      = (short*)(ws + 1114112);    //   8 MB [16][256][1024] bf16
    short* yb       = (short*)(ws + 9502720);    //  16 MB [16][256][2048] bf16

    convert_x_kernel<<<256, 256, 0, stream>>>(x, xb);
    route_kernel<<<1, 256, 0, stream>>>(rl, topk, counts, tokens, tok_e, tok_slot, tok_wt);
    gemm1_kernel<<<dim3(N_EXP, 16), 512, 0, stream>>>(xb, w1, counts, tokens, act);
    gemm2_kernel<<<dim3(N_EXP, 16), 512, 0, stream>>>(act, w2, counts, yb);
    gather_kernel<<<T_TOK, 256, 0, stream>>>(yb, topk, tok_e, tok_slot, tok_wt, (float*)d_out);
}